// Round 1
// baseline (640.755 us; speedup 1.0000x reference)
//
#include <hip/hip_runtime.h>
#include <hip/hip_bf16.h>

#define NF 256        // features (K)
#define NC 256        // clusters (N)
#define NSAMP 262144  // samples (M)
#define BM 64         // samples per workgroup
#define BK 64         // K chunk
#define NTHREADS 256  // 4 waves
#define LDAB 72       // LDS row stride in bf16 elems: 144 B = 16B-aligned, bank-shift 4/row

typedef __attribute__((ext_vector_type(8))) short short8;
typedef __attribute__((ext_vector_type(4))) float floatx4;

// fp32 -> bf16 round-to-nearest-even (inputs are finite normals; NaN path not needed)
__device__ __forceinline__ unsigned short f2bf(float f) {
    unsigned int u = __builtin_bit_cast(unsigned int, f);
    return (unsigned short)((u + 0x7FFFu + ((u >> 16) & 1u)) >> 16);
}

__global__ __launch_bounds__(NTHREADS, 3)
void cluster_soft_assign(const float* __restrict__ x,
                         const float* __restrict__ cent,
                         float* __restrict__ out)
{
    // 9216 + 36864 + 256 + 1024 + 256 = ~47.6 KB -> 3 blocks/CU
    __shared__ __align__(16) unsigned short As[BM * LDAB];
    __shared__ __align__(16) unsigned short Bs[NC * LDAB];
    __shared__ __align__(16) float xsq[BM];
    __shared__ __align__(16) float csq[NC];
    __shared__ __align__(16) float rowsum[BM];

    const int tid  = threadIdx.x;
    const int wave = tid >> 6;
    const int lane = tid & 63;
    const int quad = lane >> 4;
    const int l16  = lane & 15;
    const int arow = tid >> 4;   // 0..15 (staging row group)
    const int ac4  = tid & 15;   // float4 index within a 64-col chunk row
    const int row0 = blockIdx.x * BM;

    if (tid < BM) { xsq[tid] = 0.f; rowsum[tid] = 0.f; }
    csq[tid] = 0.f;

    floatx4 acc[4][4];
    #pragma unroll
    for (int i = 0; i < 4; ++i)
        #pragma unroll
        for (int j = 0; j < 4; ++j)
            acc[i][j] = (floatx4){0.f, 0.f, 0.f, 0.f};

    for (int kc = 0; kc < 4; ++kc) {
        const int kb = kc * BK;
        __syncthreads();  // init / previous compute done before overwriting LDS

        // ---- stage A: 64 rows x 64 feats, fp32 -> bf16, accumulate x^2 ----
        #pragma unroll
        for (int i = 0; i < 4; ++i) {
            const int r = arow + 16 * i;
            const floatx4 v = *(const floatx4*)(x + (size_t)(row0 + r) * NF + kb + ac4 * 4);
            float s = v.x * v.x + v.y * v.y + v.z * v.z + v.w * v.w;
            s += __shfl_xor(s, 1);
            s += __shfl_xor(s, 2);
            s += __shfl_xor(s, 4);
            s += __shfl_xor(s, 8);
            if (l16 == 0) xsq[r] += s;   // unique (thread,row) writer per chunk; barrier-separated
            ushort4 b;
            b.x = f2bf(v.x); b.y = f2bf(v.y); b.z = f2bf(v.z); b.w = f2bf(v.w);
            *(ushort4*)(As + r * LDAB + ac4 * 4) = b;
        }
        // ---- stage B: 256 clusters x 64 feats, fp32 -> bf16, accumulate c^2 ----
        #pragma unroll
        for (int i = 0; i < 16; ++i) {
            const int r = arow + 16 * i;
            const floatx4 v = *(const floatx4*)(cent + (size_t)r * NF + kb + ac4 * 4);
            float s = v.x * v.x + v.y * v.y + v.z * v.z + v.w * v.w;
            s += __shfl_xor(s, 1);
            s += __shfl_xor(s, 2);
            s += __shfl_xor(s, 4);
            s += __shfl_xor(s, 8);
            if (l16 == 0) csq[r] += s;
            ushort4 b;
            b.x = f2bf(v.x); b.y = f2bf(v.y); b.z = f2bf(v.z); b.w = f2bf(v.w);
            *(ushort4*)(Bs + r * LDAB + ac4 * 4) = b;
        }
        __syncthreads();

        // ---- MFMA: wave covers cols [wave*64, wave*64+64), all 64 rows ----
        #pragma unroll
        for (int s = 0; s < 2; ++s) {
            const int ko = s * 32 + quad * 8;  // A[m][k]: m=l16, k=quad*8+j (16x16x32 layout)
            short8 bfr[4];
            #pragma unroll
            for (int j = 0; j < 4; ++j)
                bfr[j] = *(const short8*)(Bs + (wave * 64 + j * 16 + l16) * LDAB + ko);
            #pragma unroll
            for (int i = 0; i < 4; ++i) {
                const short8 afr = *(const short8*)(As + (i * 16 + l16) * LDAB + ko);
                #pragma unroll
                for (int j = 0; j < 4; ++j)
                    acc[i][j] = __builtin_amdgcn_mfma_f32_16x16x32_bf16(afr, bfr[j], acc[i][j], 0, 0, 0);
            }
        }
    }

    // ---- epilogue: d = x^2 - 2*cross + c^2; q = 1/(1+d); row-normalize ----
    // C/D layout (m89-verified): col = lane&15, row = quad*4 + reg
    float csv[4];
    #pragma unroll
    for (int j = 0; j < 4; ++j) csv[j] = csq[wave * 64 + j * 16 + l16];

    float rs[4][4];
    #pragma unroll
    for (int i = 0; i < 4; ++i) {
        const floatx4 xv = *(const floatx4*)(xsq + i * 16 + quad * 4);
        #pragma unroll
        for (int reg = 0; reg < 4; ++reg) rs[i][reg] = 0.f;
        #pragma unroll
        for (int j = 0; j < 4; ++j) {
            #pragma unroll
            for (int reg = 0; reg < 4; ++reg) {
                float d = xv[reg] - 2.f * acc[i][j][reg] + csv[j];
                d = fmaxf(d, 0.f);
                const float q = __builtin_amdgcn_rcpf(1.f + d);
                acc[i][j][reg] = q;
                rs[i][reg] += q;
            }
        }
    }
    // row sums: butterfly over the 16 lanes sharing a row, then one LDS atomic per (quad,row)
    #pragma unroll
    for (int i = 0; i < 4; ++i) {
        #pragma unroll
        for (int reg = 0; reg < 4; ++reg) {
            float v = rs[i][reg];
            v += __shfl_xor(v, 1);
            v += __shfl_xor(v, 2);
            v += __shfl_xor(v, 4);
            v += __shfl_xor(v, 8);
            if (l16 == 0) atomicAdd(&rowsum[i * 16 + quad * 4 + reg], v);
        }
    }
    __syncthreads();

    #pragma unroll
    for (int i = 0; i < 4; ++i) {
        const floatx4 rv = *(const floatx4*)(rowsum + i * 16 + quad * 4);
        floatx4 inv;
        #pragma unroll
        for (int reg = 0; reg < 4; ++reg) inv[reg] = __builtin_amdgcn_rcpf(rv[reg]);
        float* orow = out + (size_t)(row0 + i * 16 + quad * 4) * NC + wave * 64 + l16;
        #pragma unroll
        for (int j = 0; j < 4; ++j)
            #pragma unroll
            for (int reg = 0; reg < 4; ++reg)
                orow[(size_t)reg * NC + j * 16] = acc[i][j][reg] * inv[reg];
    }
}

extern "C" void kernel_launch(void* const* d_in, const int* in_sizes, int n_in,
                              void* d_out, int out_size, void* d_ws, size_t ws_size,
                              hipStream_t stream) {
    const float* x    = (const float*)d_in[0];
    const float* cent = (const float*)d_in[1];
    float* out        = (float*)d_out;
    dim3 grid(NSAMP / BM);   // 4096 workgroups
    dim3 block(NTHREADS);
    cluster_soft_assign<<<grid, block, 0, stream>>>(x, cent, out);
}

// Round 2
// 455.611 us; speedup vs baseline: 1.4064x; 1.4064x over previous
//
#include <hip/hip_runtime.h>
#include <hip/hip_bf16.h>

#define NF 256        // features (K)
#define NC 256        // clusters (N)
#define NSAMP 262144  // samples (M)
#define BM 64         // samples per workgroup
#define NTHREADS 512  // 8 waves; wave w owns output cols [w*32, w*32+32)
#define LDA 264       // LDS A row stride (bf16): 528 B/row -> 16B-aligned, bank shift 4/row (2-way = free)

typedef __attribute__((ext_vector_type(8))) short short8;
typedef __attribute__((ext_vector_type(4))) float floatx4;

// fp32 -> bf16 round-to-nearest-even (finite inputs)
__device__ __forceinline__ unsigned short f2bf(float f) {
    unsigned int u = __builtin_bit_cast(unsigned int, f);
    return (unsigned short)((u + 0x7FFFu + ((u >> 16) & 1u)) >> 16);
}

// ---- prep: centroids fp32 -> bf16 image (row-major [NC][NF]) + csq, once per launch ----
__global__ __launch_bounds__(64)
void prep_centroids(const float* __restrict__ cent,
                    unsigned short* __restrict__ cbf,
                    float* __restrict__ csq)
{
    const int row  = blockIdx.x;    // 0..255
    const int lane = threadIdx.x;   // 0..63
    const floatx4 v = *(const floatx4*)(cent + (size_t)row * NF + lane * 4);
    ushort4 b;
    b.x = f2bf(v.x); b.y = f2bf(v.y); b.z = f2bf(v.z); b.w = f2bf(v.w);
    *(ushort4*)(cbf + (size_t)row * NF + lane * 4) = b;
    float s = v.x * v.x + v.y * v.y + v.z * v.z + v.w * v.w;
    s += __shfl_xor(s, 1);
    s += __shfl_xor(s, 2);
    s += __shfl_xor(s, 4);
    s += __shfl_xor(s, 8);
    s += __shfl_xor(s, 16);
    s += __shfl_xor(s, 32);
    if (lane == 0) csq[row] = s;
}

// ---- main: per block, 64 samples x all 256 clusters; B persistent in registers ----
__global__ __launch_bounds__(NTHREADS, 4)   // cap 128 VGPR -> 2 blocks/CU (16 waves)
void cluster_soft_assign(const float* __restrict__ x,
                         const unsigned short* __restrict__ cbf,
                         const float* __restrict__ csq,
                         float* __restrict__ out)
{
    __shared__ __align__(16) unsigned short As[BM * LDA];  // 33792 B
    __shared__ __align__(16) float xsq[BM];
    __shared__ __align__(16) float rowsum[BM];

    const int tid  = threadIdx.x;
    const int wave = tid >> 6;      // 0..7
    const int lane = tid & 63;
    const int quad = lane >> 4;
    const int l16  = lane & 15;
    const int row0 = blockIdx.x * BM;

    // ---- stage A: 64 rows x 256 feats fp32->bf16 into LDS; xsq as side product ----
    const int srow = tid >> 3;      // 0..63
    const int sc   = tid & 7;       // 0..7
    {
        float s = 0.f;
        #pragma unroll
        for (int i = 0; i < 8; ++i) {
            const floatx4 v = *(const floatx4*)(x + (size_t)(row0 + srow) * NF + (sc + 8 * i) * 4);
            s += v.x * v.x + v.y * v.y + v.z * v.z + v.w * v.w;
            ushort4 b;
            b.x = f2bf(v.x); b.y = f2bf(v.y); b.z = f2bf(v.z); b.w = f2bf(v.w);
            *(ushort4*)(As + srow * LDA + (sc + 8 * i) * 4) = b;
        }
        s += __shfl_xor(s, 1);
        s += __shfl_xor(s, 2);
        s += __shfl_xor(s, 4);
        if (sc == 0) xsq[srow] = s;
    }
    if (tid < BM) rowsum[tid] = 0.f;

    // ---- B fragments: wave's 32 cols x K=256, straight from L2-resident bf16 image ----
    // B[n][k] operand layout: n = l16 (+tile), k = quad*8 + j  (16x16x32, m89-verified)
    short8 bfr[2][8];
    #pragma unroll
    for (int j = 0; j < 2; ++j)
        #pragma unroll
        for (int kk = 0; kk < 8; ++kk)
            bfr[j][kk] = *(const short8*)(cbf + ((wave * 32 + j * 16 + l16) << 8) + kk * 32 + quad * 8);

    __syncthreads();

    // ---- MFMA: 4 row-tiles x 2 col-tiles x 8 K-steps ----
    floatx4 acc[4][2];
    #pragma unroll
    for (int i = 0; i < 4; ++i) {
        acc[i][0] = (floatx4){0.f, 0.f, 0.f, 0.f};
        acc[i][1] = (floatx4){0.f, 0.f, 0.f, 0.f};
    }
    #pragma unroll
    for (int kk = 0; kk < 8; ++kk) {
        #pragma unroll
        for (int i = 0; i < 4; ++i) {
            const short8 afr = *(const short8*)(As + (i * 16 + l16) * LDA + kk * 32 + quad * 8);
            acc[i][0] = __builtin_amdgcn_mfma_f32_16x16x32_bf16(afr, bfr[0][kk], acc[i][0], 0, 0, 0);
            acc[i][1] = __builtin_amdgcn_mfma_f32_16x16x32_bf16(afr, bfr[1][kk], acc[i][1], 0, 0, 0);
        }
    }

    // ---- epilogue: d = x^2 - 2*cross + c^2; q = 1/(1+d); row-normalize ----
    // C/D layout: col = l16 (+tile), row = quad*4 + reg
    float csv[2];
    csv[0] = csq[wave * 32 + l16];
    csv[1] = csq[wave * 32 + 16 + l16];

    float rs[4][4];
    #pragma unroll
    for (int i = 0; i < 4; ++i) {
        const floatx4 xv = *(const floatx4*)(xsq + i * 16 + quad * 4);
        #pragma unroll
        for (int reg = 0; reg < 4; ++reg) rs[i][reg] = 0.f;
        #pragma unroll
        for (int j = 0; j < 2; ++j) {
            #pragma unroll
            for (int reg = 0; reg < 4; ++reg) {
                float d = xv[reg] - 2.f * acc[i][j][reg] + csv[j];
                d = fmaxf(d, 0.f);
                const float q = __builtin_amdgcn_rcpf(1.f + d);
                acc[i][j][reg] = q;
                rs[i][reg] += q;
            }
        }
    }
    // per-row partial sums: butterfly over the 16 lanes sharing a row, one LDS atomic per wave/row
    #pragma unroll
    for (int i = 0; i < 4; ++i) {
        #pragma unroll
        for (int reg = 0; reg < 4; ++reg) {
            float v = rs[i][reg];
            v += __shfl_xor(v, 1);
            v += __shfl_xor(v, 2);
            v += __shfl_xor(v, 4);
            v += __shfl_xor(v, 8);
            if (l16 == 0) atomicAdd(&rowsum[i * 16 + quad * 4 + reg], v);
        }
    }
    __syncthreads();

    #pragma unroll
    for (int i = 0; i < 4; ++i) {
        const floatx4 rv = *(const floatx4*)(rowsum + i * 16 + quad * 4);
        floatx4 inv;
        #pragma unroll
        for (int reg = 0; reg < 4; ++reg) inv[reg] = __builtin_amdgcn_rcpf(rv[reg]);
        float* orow = out + (size_t)(row0 + i * 16 + quad * 4) * NC + wave * 32 + l16;
        #pragma unroll
        for (int j = 0; j < 2; ++j)
            #pragma unroll
            for (int reg = 0; reg < 4; ++reg)
                orow[(size_t)reg * NC + j * 16] = acc[i][j][reg] * inv[reg];
    }
}

extern "C" void kernel_launch(void* const* d_in, const int* in_sizes, int n_in,
                              void* d_out, int out_size, void* d_ws, size_t ws_size,
                              hipStream_t stream) {
    const float* x    = (const float*)d_in[0];
    const float* cent = (const float*)d_in[1];
    float* out        = (float*)d_out;

    unsigned short* cbf = (unsigned short*)d_ws;                       // 256*256*2 = 128 KB
    float* csq          = (float*)((char*)d_ws + (size_t)NC * NF * 2); // +1 KB

    prep_centroids<<<dim3(NC), dim3(64), 0, stream>>>(cent, cbf, csq);
    cluster_soft_assign<<<dim3(NSAMP / BM), dim3(NTHREADS), 0, stream>>>(x, cbf, csq, out);
}